// Round 1
// baseline (11213.649 us; speedup 1.0000x reference)
//
#include <hip/hip_runtime.h>
#include <hip/hip_fp16.h>
#include <cstdint>
#include <cstddef>

#define BATCH 2
#define SEQ   2048
#define DMOD  2304
#define NHQ   8
#define NHKV  4
#define HDIM  256
#define FDIM  9216
#define NROWS (BATCH*SEQ)   // 4096

typedef unsigned short u16;
typedef unsigned int   u32;
typedef __attribute__((ext_vector_type(4))) unsigned short us4;
typedef __attribute__((ext_vector_type(8))) short s8v;
typedef __attribute__((ext_vector_type(4))) float f4v;
typedef __attribute__((ext_vector_type(4))) _Float16 h4v;

__device__ __forceinline__ u16 f2bf(float f) {
  u32 u = __builtin_bit_cast(u32, f);
  u32 r = (u + 0x7fffu + ((u >> 16) & 1u)) >> 16;
  return (u16)r;
}
__device__ __forceinline__ float bf2f(u16 h) {
  u32 u = ((u32)h) << 16;
  return __builtin_bit_cast(float, u);
}
__device__ __forceinline__ float fast_tanh(float t) {
  t = fminf(fmaxf(t, -10.f), 10.f);
  float e = __expf(t + t);
  return (e - 1.f) * __builtin_amdgcn_rcpf(e + 1.f);
}

// ---------------- GEMM: A bf16 (M=4096 x K row-major), B f32 (K x N row-major),
// inline f32->bf16 staging, 128x128 tile, BK=32, 16x16x32 bf16 MFMA ----------
#define LDSTR 40   // 32 + 8 pad (80B rows -> 20-bank rotation, 2-way max = free)

__device__ __forceinline__ void stage_A(const u16* __restrict__ A, u16* As, int K, int m0, int k0, int tid) {
  int c = tid;
  #pragma unroll
  for (int cc = 0; cc < 2; ++cc, c += 256) {
    int row = c >> 2, kc = c & 3;
    const u16* src = A + (size_t)(m0 + row) * K + k0 + kc * 8;
    us4 v0 = *(const us4*)src;
    us4 v1 = *(const us4*)(src + 4);
    u16* dst = As + row * LDSTR + kc * 8;
    *(us4*)dst = v0;
    *(us4*)(dst + 4) = v1;
  }
}

__device__ __forceinline__ void stage_B(const float* __restrict__ B, u16* Bs, int N, int k0, int n0, int tid) {
  int nn = tid & 127, kh = tid >> 7;
  const float* src = B + (size_t)(k0 + kh * 16) * N + n0 + nn;
  u16 tmp[16];
  #pragma unroll
  for (int j = 0; j < 16; ++j) tmp[j] = f2bf(src[(size_t)j * N]);
  u16* dst = Bs + nn * LDSTR + kh * 16;
  #pragma unroll
  for (int j4 = 0; j4 < 4; ++j4) {
    us4 v = { tmp[j4*4+0], tmp[j4*4+1], tmp[j4*4+2], tmp[j4*4+3] };
    *(us4*)(dst + j4 * 4) = v;
  }
}

__device__ __forceinline__ s8v frag_load(const u16* p) {
  union { us4 h[2]; s8v v; } u;
  u.h[0] = *(const us4*)p;
  u.h[1] = *(const us4*)(p + 4);
  return u.v;
}

// EPI 0: f32 plain row-major out.  EPI 1: fp16 out in (B, H=N/256, S, 256) attn layout, *scale.
template<int EPI>
__global__ __launch_bounds__(256) void gemm_k(const u16* __restrict__ A, const float* __restrict__ B,
                                              void* __restrict__ C, int N, int K, float scale)
{
  __shared__ u16 As[128 * LDSTR];
  __shared__ u16 Bs[128 * LDSTR];
  int tid = threadIdx.x;
  int mt = blockIdx.x & 31, nt = blockIdx.x >> 5;   // M fixed = 4096 -> 32 m-tiles, mt fastest (B-panel reuse)
  int m0 = mt << 7, n0 = nt << 7;
  int lane = tid & 63, wid = tid >> 6;
  int wrow = wid >> 1, wcol = wid & 1;
  int lrow = lane & 15, quad = lane >> 4;
  f4v acc[4][4] = {};
  for (int k0 = 0; k0 < K; k0 += 32) {
    __syncthreads();
    stage_A(A, As, K, m0, k0, tid);
    stage_B(B, Bs, N, k0, n0, tid);
    __syncthreads();
    s8v af[4], bfv[4];
    #pragma unroll
    for (int i = 0; i < 4; ++i)
      af[i] = frag_load(As + (wrow*64 + i*16 + lrow) * LDSTR + quad * 8);
    #pragma unroll
    for (int j = 0; j < 4; ++j)
      bfv[j] = frag_load(Bs + (wcol*64 + j*16 + lrow) * LDSTR + quad * 8);
    #pragma unroll
    for (int i = 0; i < 4; ++i)
      #pragma unroll
      for (int j = 0; j < 4; ++j)
        acc[i][j] = __builtin_amdgcn_mfma_f32_16x16x32_bf16(af[i], bfv[j], acc[i][j], 0, 0, 0);
  }
  #pragma unroll
  for (int i = 0; i < 4; ++i) {
    #pragma unroll
    for (int j = 0; j < 4; ++j) {
      int col = n0 + wcol*64 + j*16 + lrow;
      #pragma unroll
      for (int r = 0; r < 4; ++r) {
        int row = m0 + wrow*64 + i*16 + quad*4 + r;   // C/D: col=lane&15, row=quad*4+reg (m89)
        float val = acc[i][j][r] * scale;
        if (EPI == 0) {
          ((float*)C)[(size_t)row * N + col] = val;
        } else {
          int b = row >> 11, s = row & 2047, hh = col >> 8, hd = col & 255;
          ((_Float16*)C)[((((size_t)b * (N >> 8) + hh) * SEQ + s) << 8) + hd] = (_Float16)val;
        }
      }
    }
  }
}

// dual-B GEMM for FFW: C = bf16( gelu_tanh(A@B0) * (A@B1) ), plain row-major
__global__ __launch_bounds__(256) void gemm_dual_k(const u16* __restrict__ A, const float* __restrict__ B0,
                                                   const float* __restrict__ B1, u16* __restrict__ C,
                                                   int N, int K)
{
  __shared__ u16 As[128 * LDSTR];
  __shared__ u16 B0s[128 * LDSTR];
  __shared__ u16 B1s[128 * LDSTR];
  int tid = threadIdx.x;
  int mt = blockIdx.x & 31, nt = blockIdx.x >> 5;
  int m0 = mt << 7, n0 = nt << 7;
  int lane = tid & 63, wid = tid >> 6;
  int wrow = wid >> 1, wcol = wid & 1;
  int lrow = lane & 15, quad = lane >> 4;
  f4v acc0[4][4] = {}, acc1[4][4] = {};
  for (int k0 = 0; k0 < K; k0 += 32) {
    __syncthreads();
    stage_A(A, As, K, m0, k0, tid);
    stage_B(B0, B0s, N, k0, n0, tid);
    stage_B(B1, B1s, N, k0, n0, tid);
    __syncthreads();
    s8v af[4], b0v[4], b1v[4];
    #pragma unroll
    for (int i = 0; i < 4; ++i)
      af[i] = frag_load(As + (wrow*64 + i*16 + lrow) * LDSTR + quad * 8);
    #pragma unroll
    for (int j = 0; j < 4; ++j) {
      b0v[j] = frag_load(B0s + (wcol*64 + j*16 + lrow) * LDSTR + quad * 8);
      b1v[j] = frag_load(B1s + (wcol*64 + j*16 + lrow) * LDSTR + quad * 8);
    }
    #pragma unroll
    for (int i = 0; i < 4; ++i)
      #pragma unroll
      for (int j = 0; j < 4; ++j) {
        acc0[i][j] = __builtin_amdgcn_mfma_f32_16x16x32_bf16(af[i], b0v[j], acc0[i][j], 0, 0, 0);
        acc1[i][j] = __builtin_amdgcn_mfma_f32_16x16x32_bf16(af[i], b1v[j], acc1[i][j], 0, 0, 0);
      }
  }
  #pragma unroll
  for (int i = 0; i < 4; ++i) {
    #pragma unroll
    for (int j = 0; j < 4; ++j) {
      int col = n0 + wcol*64 + j*16 + lrow;
      #pragma unroll
      for (int r = 0; r < 4; ++r) {
        int row = m0 + wrow*64 + i*16 + quad*4 + r;
        float x = acc0[i][j][r];
        float g = 0.5f * x * (1.f + fast_tanh(0.7978845608028654f * (x + 0.044715f * x * x * x)));
        C[(size_t)row * N + col] = f2bf(g * acc1[i][j][r]);
      }
    }
  }
}

// ---------------- RMS / fuse / rope / attention ----------------

__global__ __launch_bounds__(256) void rms_bf16_k(const float* __restrict__ x, const float* __restrict__ w,
                                                  u16* __restrict__ h)
{
  __shared__ float sbuf[4];
  int r = blockIdx.x, tid = threadIdx.x;
  int lane = tid & 63, wid = tid >> 6;
  const float* xr = x + (size_t)r * DMOD;
  float v[9]; float ss = 0.f;
  #pragma unroll
  for (int j = 0; j < 9; ++j) { v[j] = xr[tid + j*256]; ss += v[j]*v[j]; }
  #pragma unroll
  for (int off = 32; off > 0; off >>= 1) ss += __shfl_xor(ss, off);
  if (lane == 0) sbuf[wid] = ss;
  __syncthreads();
  float sc = rsqrtf((sbuf[0]+sbuf[1]+sbuf[2]+sbuf[3]) * (1.f/2304.f) + 1e-6f);
  #pragma unroll
  for (int j = 0; j < 9; ++j) {
    int d = tid + j*256;
    h[(size_t)r * DMOD + d] = f2bf(v[j] * sc * w[d]);
  }
}

// x1 = xin + rms(proj, wpost); write x1 -> xout (f32); if wnext: hout = bf16(rms(x1, wnext))
__global__ __launch_bounds__(256) void fuse_k(const float* __restrict__ proj, const float* __restrict__ xin,
                                              float* __restrict__ xout, const float* __restrict__ wpost,
                                              const float* __restrict__ wnext, u16* __restrict__ hout)
{
  __shared__ float sbuf[4];
  int r = blockIdx.x, tid = threadIdx.x;
  int lane = tid & 63, wid = tid >> 6;
  const float* pr = proj + (size_t)r * DMOD;
  const float* xr = xin + (size_t)r * DMOD;
  float p[9]; float ss = 0.f;
  #pragma unroll
  for (int j = 0; j < 9; ++j) { p[j] = pr[tid + j*256]; ss += p[j]*p[j]; }
  #pragma unroll
  for (int off = 32; off > 0; off >>= 1) ss += __shfl_xor(ss, off);
  if (lane == 0) sbuf[wid] = ss;
  __syncthreads();
  float sc = rsqrtf((sbuf[0]+sbuf[1]+sbuf[2]+sbuf[3]) * (1.f/2304.f) + 1e-6f);
  float x1[9]; float ss2 = 0.f;
  #pragma unroll
  for (int j = 0; j < 9; ++j) {
    int d = tid + j*256;
    float v = xr[d] + p[j] * sc * wpost[d];
    x1[j] = v; ss2 += v*v;
    xout[(size_t)r * DMOD + d] = v;
  }
  if (wnext) {
    #pragma unroll
    for (int off = 32; off > 0; off >>= 1) ss2 += __shfl_xor(ss2, off);
    __syncthreads();                       // ensure sbuf reads above are done
    if (lane == 0) sbuf[wid] = ss2;
    __syncthreads();
    float sc2 = rsqrtf((sbuf[0]+sbuf[1]+sbuf[2]+sbuf[3]) * (1.f/2304.f) + 1e-6f);
    #pragma unroll
    for (int j = 0; j < 9; ++j) {
      int d = tid + j*256;
      hout[(size_t)r * DMOD + d] = f2bf(x1[j] * sc2 * wnext[d]);
    }
  }
}

// in-place RoPE on fp16 buffer in (B, H, S, 256) layout; one thread per (b,h,s,i<128) pair
__global__ __launch_bounds__(256) void rope_k(_Float16* __restrict__ buf, const int* __restrict__ positions,
                                              int hshift)
{
  int id = blockIdx.x * 256 + threadIdx.x;
  int i = id & 127;
  int r = id >> 7;               // (b*H + h)*S + s
  int s = r & 2047;
  int b = (r >> 11) >> hshift;
  int pos = positions[(b << 11) + s];
  float freq = __expf(-(float)i * 0.07195578415606394f);   // ln(10000)/128
  float ang = (float)pos * freq;
  float sv, cv;
  sincosf(ang, &sv, &cv);
  _Float16* p = buf + ((size_t)r << 8) + i;
  float x1 = (float)p[0], x2 = (float)p[128];
  p[0]   = (_Float16)(x1 * cv - x2 * sv);
  p[128] = (_Float16)(x2 * cv + x1 * sv);
}

// vector flash attention: one wave per (b, h, q); online softmax; tanh softcap 50
__global__ __launch_bounds__(256) void attn_k(const _Float16* __restrict__ qb, const _Float16* __restrict__ kb,
                                              const _Float16* __restrict__ vb, const int* __restrict__ positions,
                                              const int* __restrict__ segs, u16* __restrict__ ob, int window)
{
  int gw = (blockIdx.x * 256 + threadIdx.x) >> 6;
  int lane = threadIdx.x & 63;
  int q = gw & 2047, h = (gw >> 11) & 7, b = gw >> 14;
  int d0 = lane << 2;
  const _Float16* qp = qb + ((((size_t)b * NHQ + h) * SEQ + q) << 8) + d0;
  h4v qh = *(const h4v*)qp;
  float q0 = (float)qh[0], q1 = (float)qh[1], q2 = (float)qh[2], q3 = (float)qh[3];
  const _Float16* kbase = kb + (((size_t)b * NHKV + (h >> 1)) * SEQ << 8);
  const _Float16* vbase = vb + (((size_t)b * NHKV + (h >> 1)) * SEQ << 8);
  int pos_q = positions[(b << 11) + q];
  int seg_q = segs[(b << 11) + q];
  int s_lo = q - window + 1; if (s_lo < 0) s_lo = 0;
  float mi = -3.0e38f, l = 0.f, a0 = 0.f, a1 = 0.f, a2 = 0.f, a3 = 0.f;
  for (int s = s_lo; s <= q; ++s) {
    h4v kh = *(const h4v*)(kbase + ((size_t)s << 8) + d0);
    float part = q0*(float)kh[0] + q1*(float)kh[1] + q2*(float)kh[2] + q3*(float)kh[3];
    #pragma unroll
    for (int off = 32; off > 0; off >>= 1) part += __shfl_xor(part, off);
    int pk = positions[(b << 11) + s];
    int sk = segs[(b << 11) + s];
    bool valid = (pos_q >= pk) && (seg_q == sk) && ((pos_q - pk) < window);
    if (!valid) continue;
    float logit = 50.f * fast_tanh(part * 0.02f);
    if (logit > mi) {
      float alpha = __expf(mi - logit);
      l *= alpha; a0 *= alpha; a1 *= alpha; a2 *= alpha; a3 *= alpha;
      mi = logit;
    }
    float p = __expf(logit - mi);
    h4v vh = *(const h4v*)(vbase + ((size_t)s << 8) + d0);
    l += p;
    a0 += p*(float)vh[0]; a1 += p*(float)vh[1]; a2 += p*(float)vh[2]; a3 += p*(float)vh[3];
  }
  float inv = 1.0f / l;
  u16* op = ob + ((size_t)((b << 11) + q) * 2048) + (h << 8) + d0;
  us4 o4 = { f2bf(a0*inv), f2bf(a1*inv), f2bf(a2*inv), f2bf(a3*inv) };
  *(us4*)op = o4;
}

// ---------------- driver ----------------
extern "C" void kernel_launch(void* const* d_in, const int* in_sizes, int n_in,
                              void* d_out, int out_size, void* d_ws, size_t ws_size,
                              hipStream_t stream) {
  const float* x         = (const float*)d_in[0];
  const int*   positions = (const int*)d_in[1];
  const int*   segs      = (const int*)d_in[2];
  const float* w_rms[8]  = { (const float*)d_in[3], (const float*)d_in[4], (const float*)d_in[5], (const float*)d_in[6],
                             (const float*)d_in[14], (const float*)d_in[15], (const float*)d_in[16], (const float*)d_in[17] };
  const float* wq[2]  = { (const float*)d_in[7],  (const float*)d_in[18] };
  const float* wk[2]  = { (const float*)d_in[8],  (const float*)d_in[19] };
  const float* wv[2]  = { (const float*)d_in[9],  (const float*)d_in[20] };
  const float* wo[2]  = { (const float*)d_in[10], (const float*)d_in[21] };
  const float* wi0[2] = { (const float*)d_in[11], (const float*)d_in[22] };
  const float* wi1[2] = { (const float*)d_in[12], (const float*)d_in[23] };
  const float* wom[2] = { (const float*)d_in[13], (const float*)d_in[24] };

  size_t off = 0;
  char* wsb = (char*)d_ws;
  auto alloc = [&](size_t bytes) { void* p = wsb + off; off += (bytes + 255) & ~(size_t)255; return p; };
  u16*       hbuf = (u16*)      alloc((size_t)NROWS * DMOD * 2);       // 18.9 MB
  _Float16*  qb   = (_Float16*) alloc((size_t)BATCH*NHQ*SEQ*HDIM * 2); // 16.8 MB
  _Float16*  kbv  = (_Float16*) alloc((size_t)BATCH*NHKV*SEQ*HDIM * 2);// 8.4 MB
  _Float16*  vbv  = (_Float16*) alloc((size_t)BATCH*NHKV*SEQ*HDIM * 2);// 8.4 MB
  u16*       obuf = (u16*)      alloc((size_t)NROWS * (NHQ*HDIM) * 2); // 16.8 MB
  float*     proj = (float*)    alloc((size_t)NROWS * DMOD * 4);       // 37.7 MB
  u16*       mbuf = (u16*)      alloc((size_t)NROWS * FDIM * 2);       // 75.5 MB
  if (off > ws_size) return;  // workspace too small; fail visibly rather than corrupt

  float* xo = (float*)d_out;

  for (int blk = 0; blk < 2; ++blk) {
    const float* pre_attn  = w_rms[blk*4 + 0];
    const float* post_attn = w_rms[blk*4 + 1];
    const float* pre_ffw   = w_rms[blk*4 + 2];
    const float* post_ffw  = w_rms[blk*4 + 3];
    const float* xin = (blk == 0) ? x : xo;
    int window = (blk == 0) ? 1024 : (1 << 30);
    const float* next_pre_attn = (blk == 0) ? w_rms[4] : nullptr;

    if (blk == 0)
      rms_bf16_k<<<NROWS, 256, 0, stream>>>(xin, pre_attn, hbuf);
    // else: previous fuse_k already produced hbuf = rms(x, pre_attn_g)

    gemm_k<1><<<32*16, 256, 0, stream>>>(hbuf, wq[blk], qb,  2048, DMOD, 0.0625f); // q, *HD^-0.5
    gemm_k<1><<<32* 8, 256, 0, stream>>>(hbuf, wk[blk], kbv, 1024, DMOD, 1.0f);
    gemm_k<1><<<32* 8, 256, 0, stream>>>(hbuf, wv[blk], vbv, 1024, DMOD, 1.0f);
    rope_k<<<BATCH*NHQ*SEQ*128/256, 256, 0, stream>>>(qb,  positions, 3);
    rope_k<<<BATCH*NHKV*SEQ*128/256, 256, 0, stream>>>(kbv, positions, 2);
    attn_k<<<BATCH*NHQ*SEQ/4, 256, 0, stream>>>(qb, kbv, vbv, positions, segs, obuf, window);
    gemm_k<0><<<32*18, 256, 0, stream>>>(obuf, wo[blk], proj, DMOD, NHQ*HDIM, 1.0f);
    fuse_k<<<NROWS, 256, 0, stream>>>(proj, xin, xo, post_attn, pre_ffw, hbuf);
    gemm_dual_k<<<32*72, 256, 0, stream>>>(hbuf, wi0[blk], wi1[blk], mbuf, FDIM, DMOD);
    gemm_k<0><<<32*18, 256, 0, stream>>>(mbuf, wom[blk], proj, DMOD, FDIM, 1.0f);
    fuse_k<<<NROWS, 256, 0, stream>>>(proj, xo, xo, post_ffw, next_pre_attn, hbuf);
  }
}